// Round 7
// baseline (2549.415 us; speedup 1.0000x reference)
//
#include <hip/hip_runtime.h>
#include <cstddef>

#define NN 50000
#define NE 1600000
#define NB 500
#define TT 16

__device__ __forceinline__ float leaky(float v){ return fmaxf(v, 0.1f*v); }

__device__ __forceinline__ float sigf(float x){
    float e = __expf(-fabsf(x));
    float p = __fdividef(1.0f, 1.0f + e);
    return x >= 0.0f ? p : 1.0f - p;
}
__device__ __forceinline__ float tanhf_(float x){
    float e = __expf(-2.0f*fabsf(x));
    float p = (1.0f - e) * __fdividef(1.0f, 1.0f + e);
    return x >= 0.0f ? p : -p;
}

// ---------------------------------------------------------------------------
// Fused emb + GRU(T=16) + dyn projection.
// Block = 256 threads = 4 waves, covers 64 node rows (lane = row).
// Wave w computes gate columns u in [16w, 16w+16) -> 3128 waves (~3/SIMD).
// h exchanged per step via u-major LDS hbuf[u][row] (bank=row%32, 2-way free).
// Weight addresses wave-uniform (u in SGPR) -> scalar broadcast loads.
// ---------------------------------------------------------------------------
__global__ __launch_bounds__(256, 3) void k_gru(
    const float* __restrict__ x,      // [NN,16,2]
    const float* __restrict__ W_ip,   // [32,2]
    const float* __restrict__ b_ip,   // [32]
    const float* __restrict__ Wi,     // [192,32]
    const float* __restrict__ Wh,     // [192,64]
    const float* __restrict__ bi,     // [192]
    const float* __restrict__ bh,     // [192]
    const float* __restrict__ Wdyn,   // [64,64]
    const float* __restrict__ bdyn,   // [64]
    float* __restrict__ hist)         // [NN,64]
{
    __shared__ float smem[4096 + 2048];       // hbuf[64][64] + xbuf[32][64]
    float* hbuf = smem;                       // hbuf[u*64 + row]
    float* xbuf = smem + 4096;                // xbuf[c*64 + row]
    float* obuf = smem;                       // phase-2 alias: obuf[j*65 + row]

    const int tid  = threadIdx.x;
    const int lane = tid & 63;                                  // row within block
    const int w    = __builtin_amdgcn_readfirstlane(tid >> 6);  // wave id -> SGPR
    const int rowbase = blockIdx.x * 64;
    const int u0 = w * 16;

    // stage x[rowbase..rowbase+64) into xbuf[c][r], coalesced
    {
        const size_t gbase = (size_t)rowbase * 32;
        const int r  = tid >> 2;
        const int c0 = (tid & 3) * 8;
        #pragma unroll
        for (int q = 0; q < 2; ++q) {
            size_t gi = gbase + (size_t)tid*8 + q*4;
            float4 v = (gi + 4 <= (size_t)NN*32) ? *(const float4*)&x[gi]
                                                 : make_float4(0.f,0.f,0.f,0.f);
            xbuf[(c0 + q*4 + 0)*64 + r] = v.x;
            xbuf[(c0 + q*4 + 1)*64 + r] = v.y;
            xbuf[(c0 + q*4 + 2)*64 + r] = v.z;
            xbuf[(c0 + q*4 + 3)*64 + r] = v.w;
        }
        #pragma unroll
        for (int q = 0; q < 16; ++q) hbuf[q*256 + tid] = 0.0f;
    }
    __syncthreads();

    float h[64];
    #pragma unroll
    for (int k = 0; k < 64; ++k) h[k] = 0.0f;

    for (int t = 0; t < TT; ++t) {
        const float x0 = xbuf[(2*t  )*64 + lane];
        const float x1 = xbuf[(2*t+1)*64 + lane];
        float e_[32];
        #pragma unroll
        for (int k = 0; k < 32; ++k)
            e_[k] = leaky(W_ip[2*k]*x0 + W_ip[2*k+1]*x1 + b_ip[k]);

        for (int j = 0; j < 16; ++j) {
            const int u = u0 + j;                       // wave-uniform
            float ir = bi[u], iz = bi[64+u], in_ = bi[128+u];
            #pragma unroll
            for (int k = 0; k < 32; ++k) {
                const float ek = e_[k];
                ir  += Wi[u*32       + k]*ek;
                iz  += Wi[(64+u)*32  + k]*ek;
                in_ += Wi[(128+u)*32 + k]*ek;
            }
            float hr = bh[u], hz = bh[64+u], hn = bh[128+u];
            #pragma unroll
            for (int k = 0; k < 64; ++k) {
                const float hk = h[k];
                hr += Wh[u*64       + k]*hk;
                hz += Wh[(64+u)*64  + k]*hk;
                hn += Wh[(128+u)*64 + k]*hk;
            }
            const float rg = sigf(ir + hr);
            const float zg = sigf(iz + hz);
            const float ng = tanhf_(in_ + rg*hn);
            const float hu = hbuf[u*64 + lane];          // old h[u]
            hbuf[u*64 + lane] = (1.0f - zg)*ng + zg*hu;  // only owner wave writes u
        }
        __syncthreads();
        #pragma unroll
        for (int k = 0; k < 64; ++k) h[k] = hbuf[k*64 + lane];
        __syncthreads();
    }

    // hist = leaky(leaky(h) @ Wdyn.T + bdyn), transposed store via obuf
    float lh[64];
    #pragma unroll
    for (int k = 0; k < 64; ++k) lh[k] = leaky(h[k]);

    for (int j = u0; j < u0 + 16; ++j) {                 // wave-uniform j
        float a = bdyn[j];
        #pragma unroll
        for (int k = 0; k < 64; ++k) a += Wdyn[j*64 + k]*lh[k];
        obuf[j*65 + lane] = leaky(a);
    }
    __syncthreads();
    #pragma unroll
    for (int i = 0; i < 16; ++i) {
        const int rr = u0 + i;
        const int grow = rowbase + rr;
        if (grow < NN) hist[(size_t)grow*64 + lane] = obuf[lane*65 + rr];
    }
}

// ---------------------------------------------------------------------------
__global__ __launch_bounds__(256) void k_deg(const int* __restrict__ dst,
                                             float* __restrict__ deg)
{
    int e = blockIdx.x*256 + threadIdx.x;
    if (e < NE) atomicAdd(&deg[dst[e]], 1.0f);
}

// single-block exclusive prefix scan of (int)deg -> rowptr, cursor
__global__ __launch_bounds__(1024) void k_scan(const float* __restrict__ deg,
                                               int* __restrict__ rowptr,
                                               int* __restrict__ cursor)
{
    __shared__ int sc[1024];
    const int tid = threadIdx.x;
    const int CH = 49;                          // 49*1024 >= NN
    const int base = tid*CH;
    int s = 0;
    for (int i = 0; i < CH; ++i) {
        int idx = base + i;
        if (idx < NN) s += (int)deg[idx];
    }
    sc[tid] = s;
    __syncthreads();
    for (int off = 1; off < 1024; off <<= 1) {
        int v = (tid >= off) ? sc[tid-off] : 0;
        __syncthreads();
        sc[tid] += v;
        __syncthreads();
    }
    int run = sc[tid] - s;                      // exclusive prefix
    for (int i = 0; i < CH; ++i) {
        int idx = base + i;
        if (idx < NN) {
            rowptr[idx] = run; cursor[idx] = run;
            run += (int)deg[idx];
        }
    }
    if (tid == 1023) rowptr[NN] = run;          // tid1023 chunk empty -> run = total
}

__global__ __launch_bounds__(256) void k_dinv(float* __restrict__ deg) // -> dinv
{
    int i = blockIdx.x*256 + threadIdx.x;
    if (i < NN) deg[i] = rsqrtf(deg[i] + 1.0f);
}

__global__ __launch_bounds__(256) void k_scatter(const int* __restrict__ src,
                                                 const int* __restrict__ dst,
                                                 int* __restrict__ cursor,
                                                 int* __restrict__ ebuf)
{
    int e = blockIdx.x*256 + threadIdx.x;
    if (e < NE) {
        int pos = atomicAdd(&cursor[dst[e]], 1);
        ebuf[pos] = src[e];
    }
}

__global__ __launch_bounds__(256) void k_transpose(const float* __restrict__ W,
                                                   float* __restrict__ WT, int R, int C)
{
    int i = blockIdx.x*256 + threadIdx.x;
    if (i < R*C) { int r = i / C, c = i % C; WT[c*R + r] = W[i]; }
}

// xws = (in @ W) * dinv[row]   (pre-scaled so the gather is a pure sum)
template <int K>
__global__ __launch_bounds__(256) void k_xw(
    const float* __restrict__ in0,
    const float* __restrict__ in1,   // second half when K=128
    const float* __restrict__ WT,    // [64][K]
    const float* __restrict__ dinv,
    float* __restrict__ xws)         // [NN,64]
{
    int row = blockIdx.x*256 + threadIdx.x;
    if (row >= NN) return;
    float in[K];
    #pragma unroll
    for (int k = 0; k < 64; k += 4) {
        float4 v = *(const float4*)&in0[(size_t)row*64 + k];
        in[k] = v.x; in[k+1] = v.y; in[k+2] = v.z; in[k+3] = v.w;
    }
    if (K == 128) {
        #pragma unroll
        for (int k = 0; k < 64; k += 4) {
            float4 v = *(const float4*)&in1[(size_t)row*64 + k];
            in[64+k] = v.x; in[64+k+1] = v.y; in[64+k+2] = v.z; in[64+k+3] = v.w;
        }
    }
    const float di = dinv[row];
    float* xr = xws + (size_t)row*64;
    for (int o = 0; o < 64; ++o) {
        float a = 0.0f;
        #pragma unroll
        for (int k = 0; k < K; ++k) a += WT[o*K + k]*in[k];
        xr[o] = a*di;
    }
}

// wave per dst node; lane = feature. out = dinv[d]*(sum xws[src] + xws[d]) + b
__global__ __launch_bounds__(256) void k_gather(
    const int* __restrict__ rowptr, const int* __restrict__ ebuf,
    const float* __restrict__ dinv, const float* __restrict__ xws,
    const float* __restrict__ bg, float* __restrict__ out)
{
    const int lane = threadIdx.x & 63;
    const int node = (blockIdx.x*256 + threadIdx.x) >> 6;
    if (node >= NN) return;
    const int s0 = rowptr[node], s1 = rowptr[node+1];
    float a0 = 0.f, a1 = 0.f, a2 = 0.f, a3 = 0.f;
    int j = s0;
    for (; j + 4 <= s1; j += 4) {
        const int e0 = ebuf[j], e1 = ebuf[j+1], e2 = ebuf[j+2], e3 = ebuf[j+3];
        a0 += xws[(size_t)e0*64 + lane];
        a1 += xws[(size_t)e1*64 + lane];
        a2 += xws[(size_t)e2*64 + lane];
        a3 += xws[(size_t)e3*64 + lane];
    }
    for (; j < s1; ++j) a0 += xws[(size_t)ebuf[j]*64 + lane];
    const float acc = ((a0+a1) + (a2+a3)) + xws[(size_t)node*64 + lane];
    out[(size_t)node*64 + lane] = dinv[node]*acc + bg[lane];
}

// ---------------------------------------------------------------------------
__global__ __launch_bounds__(128) void k_target(
    const int* __restrict__ tgt,
    const float* __restrict__ hist, const float* __restrict__ g1,
    const float* __restrict__ g2,
    const float* __restrict__ Wnbr, const float* __restrict__ bnbr, // [64,128],[64]
    const float* __restrict__ Wi0,  const float* __restrict__ bi0,  // [512,128],[512]
    float* __restrict__ iga0)                                       // [NB,512]
{
    __shared__ float feat[128];
    __shared__ float enc[128];
    const int b = blockIdx.x, t = threadIdx.x;
    const int n = tgt[b];
    if (t < 64) {
        feat[t]    = g1[(size_t)n*64 + t];
        feat[64+t] = g2[(size_t)n*64 + t];
        enc[t]     = hist[(size_t)n*64 + t];
    }
    __syncthreads();
    if (t < 64) {
        float a = bnbr[t];
        #pragma unroll 16
        for (int k = 0; k < 128; ++k) a += Wnbr[t*128 + k]*feat[k];
        enc[64+t] = leaky(a);
    }
    __syncthreads();
    #pragma unroll
    for (int rep = 0; rep < 4; ++rep) {
        const int o = t + rep*128;
        float a = bi0[o];
        #pragma unroll 16
        for (int k = 0; k < 128; ++k) a += Wi0[o*128 + k]*enc[k];
        iga0[(size_t)b*512 + o] = a;
    }
}

// ---------------------------------------------------------------------------
// 2-layer LSTM decoder, 25 steps. 125 blocks x 512 threads, 4 rows/block.
// Per-block weight stream = 768KB/step from L2 regardless of rows, so fewer
// blocks => less L2 traffic: 125 x 19.2MB = 2.4GB (~70us floor) vs 4.8GB at
// 250 blocks. Per-row arithmetic identical to the 2-row version (same dot
// expressions and order) -- only the thread->row mapping changed.
// ---------------------------------------------------------------------------
__global__ __launch_bounds__(512) void k_lstm(
    const float* __restrict__ iga0,  // [NB,512] = enc@Wi0.T + bi0
    const float* __restrict__ bh0,   // [512]
    const float* __restrict__ Wh0,   // [512,128]
    const float* __restrict__ Wi1,   // [512,128]
    const float* __restrict__ Wh1,   // [512,128]
    const float* __restrict__ bi1, const float* __restrict__ bh1, // [512]
    float* __restrict__ hdec)        // [NB,25,128]
{
    __shared__ float h0[4][128], h1[4][128], g[4][512];
    const int t  = threadIdx.x;
    const int b0 = blockIdx.x*4;
    const int r  = t >> 7;          // row updated by this thread (0..3)
    const int u  = t & 127;         // unit within row

    if (t < 128) {
        #pragma unroll
        for (int q = 0; q < 4; ++q) { h0[q][t] = 0.f; h1[q][t] = 0.f; }
    }
    float c0 = 0.f, c1 = 0.f;       // cell state of (r,u) for this thread
    float ig[4];
    #pragma unroll
    for (int q = 0; q < 4; ++q)
        ig[q] = iga0[(size_t)(b0+q)*512 + t] + bh0[t];
    const float bL1 = bi1[t] + bh1[t];
    __syncthreads();

    for (int s = 0; s < 25; ++s) {
        // ---- layer 0 gates: g[q] = ig[q] + h0[q] @ Wh0.T ----
        float a0 = ig[0], a1 = ig[1], a2 = ig[2], a3 = ig[3];
        #pragma unroll 4
        for (int k = 0; k < 128; k += 4) {
            const float4 w  = *(const float4*)&Wh0[(size_t)t*128 + k];
            const float4 p0 = *(const float4*)&h0[0][k];
            const float4 p1 = *(const float4*)&h0[1][k];
            const float4 p2 = *(const float4*)&h0[2][k];
            const float4 p3 = *(const float4*)&h0[3][k];
            a0 += w.x*p0.x + w.y*p0.y + w.z*p0.z + w.w*p0.w;
            a1 += w.x*p1.x + w.y*p1.y + w.z*p1.z + w.w*p1.w;
            a2 += w.x*p2.x + w.y*p2.y + w.z*p2.z + w.w*p2.w;
            a3 += w.x*p3.x + w.y*p3.y + w.z*p3.z + w.w*p3.w;
        }
        g[0][t] = a0; g[1][t] = a1; g[2][t] = a2; g[3][t] = a3;
        __syncthreads();
        {   // update layer 0: all 512 threads, thread -> (r,u)
            const float i_ = sigf(g[r][u]);
            const float f_ = sigf(g[r][128+u]);
            const float g_ = tanhf_(g[r][256+u]);
            const float o_ = sigf(g[r][384+u]);
            c0 = f_*c0 + i_*g_;
            h0[r][u] = o_*tanhf_(c0);
        }
        __syncthreads();
        // ---- layer 1 gates: g[q] = bL1 + h0[q] @ Wi1.T + h1[q] @ Wh1.T ----
        float b0a = bL1, b1a = bL1, b2a = bL1, b3a = bL1;
        #pragma unroll 4
        for (int k = 0; k < 128; k += 4) {
            const float4 wi = *(const float4*)&Wi1[(size_t)t*128 + k];
            const float4 wh = *(const float4*)&Wh1[(size_t)t*128 + k];
            const float4 q0 = *(const float4*)&h0[0][k];
            const float4 q1 = *(const float4*)&h0[1][k];
            const float4 q2 = *(const float4*)&h0[2][k];
            const float4 q3 = *(const float4*)&h0[3][k];
            const float4 r0 = *(const float4*)&h1[0][k];
            const float4 r1 = *(const float4*)&h1[1][k];
            const float4 r2 = *(const float4*)&h1[2][k];
            const float4 r3 = *(const float4*)&h1[3][k];
            b0a += wi.x*q0.x + wi.y*q0.y + wi.z*q0.z + wi.w*q0.w
                 + wh.x*r0.x + wh.y*r0.y + wh.z*r0.z + wh.w*r0.w;
            b1a += wi.x*q1.x + wi.y*q1.y + wi.z*q1.z + wi.w*q1.w
                 + wh.x*r1.x + wh.y*r1.y + wh.z*r1.z + wh.w*r1.w;
            b2a += wi.x*q2.x + wi.y*q2.y + wi.z*q2.z + wi.w*q2.w
                 + wh.x*r2.x + wh.y*r2.y + wh.z*r2.z + wh.w*r2.w;
            b3a += wi.x*q3.x + wi.y*q3.y + wi.z*q3.z + wi.w*q3.w
                 + wh.x*r3.x + wh.y*r3.y + wh.z*r3.z + wh.w*r3.w;
        }
        g[0][t] = b0a; g[1][t] = b1a; g[2][t] = b2a; g[3][t] = b3a;
        __syncthreads();
        {   // update layer 1 + store
            const float i_ = sigf(g[r][u]);
            const float f_ = sigf(g[r][128+u]);
            const float g_ = tanhf_(g[r][256+u]);
            const float o_ = sigf(g[r][384+u]);
            c1 = f_*c1 + i_*g_;
            const float hv = o_*tanhf_(c1);
            h1[r][u] = hv;
            hdec[((size_t)(b0+r)*25 + s)*128 + u] = hv;
        }
        __syncthreads();
    }
}

__global__ __launch_bounds__(256) void k_out(
    const float* __restrict__ hdec, const float* __restrict__ Wop,
    const float* __restrict__ bop, float* __restrict__ out)
{
    const int i = blockIdx.x*256 + threadIdx.x;
    if (i >= NB*25*2) return;
    const int o = i & 1, bs = i >> 1;
    float a = bop[o];
    const float* h = hdec + (size_t)bs*128;
    #pragma unroll 16
    for (int k = 0; k < 128; ++k) a += Wop[o*128 + k]*h[k];
    out[i] = a;
}

// ---------------------------------------------------------------------------
extern "C" void kernel_launch(void* const* d_in, const int* in_sizes, int n_in,
                              void* d_out, int out_size, void* d_ws, size_t ws_size,
                              hipStream_t stream)
{
    const float* x     = (const float*)d_in[0];
    const float* W_ip  = (const float*)d_in[1];
    const float* b_ip  = (const float*)d_in[2];
    const float* gWi   = (const float*)d_in[3];
    const float* gWh   = (const float*)d_in[4];
    const float* gbi   = (const float*)d_in[5];
    const float* gbh   = (const float*)d_in[6];
    const float* Wdyn  = (const float*)d_in[7];
    const float* bdyn  = (const float*)d_in[8];
    const float* W_g1  = (const float*)d_in[9];
    const float* b_g1  = (const float*)d_in[10];
    const float* W_g2  = (const float*)d_in[11];
    const float* b_g2  = (const float*)d_in[12];
    const float* Wnbr  = (const float*)d_in[13];
    const float* bnbr  = (const float*)d_in[14];
    const float* Wi0   = (const float*)d_in[15];
    const float* Wh0   = (const float*)d_in[16];
    const float* bi0   = (const float*)d_in[17];
    const float* bh0   = (const float*)d_in[18];
    const float* Wi1   = (const float*)d_in[19];
    const float* Wh1   = (const float*)d_in[20];
    const float* bi1   = (const float*)d_in[21];
    const float* bh1   = (const float*)d_in[22];
    const float* Wop   = (const float*)d_in[23];
    const float* bop   = (const float*)d_in[24];
    const int*   eidx  = (const int*)d_in[25];
    const int*   tgt   = (const int*)d_in[26];
    const int* esrc = eidx;
    const int* edst = eidx + NE;

    float* ws   = (float*)d_ws;
    float* hist = ws;                               // 3.2M floats
    float* xws  = ws + 3200000;                     // 3.2M
    float* g1   = ws + 6400000;                     // 3.2M
    float* g2   = ws + 9600000;                     // 3.2M
    float* dinv = ws + 12800000;                    // 50K (deg -> dinv in place)
    int* rowptr = (int*)(ws + 12860000);            // 50001
    int* cursor = (int*)(ws + 12920000);            // 50000
    int* ebuf   = (int*)(ws + 12980000);            // 1.6M
    float* WT1  = ws + 14580000;                    // 4096
    float* WT2  = ws + 14590000;                    // 8192
    float* iga0 = ws + 14600000;                    // 256K
    float* hdec = xws;                              // reuse: xws dead after gather #2
    float* out  = (float*)d_out;

    hipMemsetAsync(dinv, 0, NN*sizeof(float), stream);
    k_transpose<<<16, 256, 0, stream>>>(W_g1, WT1, 64, 64);
    k_transpose<<<32, 256, 0, stream>>>(W_g2, WT2, 128, 64);
    k_deg<<<(NE+255)/256, 256, 0, stream>>>(edst, dinv);
    k_scan<<<1, 1024, 0, stream>>>(dinv, rowptr, cursor);
    k_dinv<<<(NN+255)/256, 256, 0, stream>>>(dinv);
    k_scatter<<<(NE+255)/256, 256, 0, stream>>>(esrc, edst, cursor, ebuf);

    // GRU encoder
    k_gru<<<(NN+63)/64, 256, 0, stream>>>(x, W_ip, b_ip, gWi, gWh, gbi, gbh,
                                          Wdyn, bdyn, hist);

    // GCN layer 1
    k_xw<64><<<(NN+255)/256, 256, 0, stream>>>(hist, nullptr, WT1, dinv, xws);
    k_gather<<<(NN+3)/4, 256, 0, stream>>>(rowptr, ebuf, dinv, xws, b_g1, g1);
    // GCN layer 2 (input concat(hist, g1))
    k_xw<128><<<(NN+255)/256, 256, 0, stream>>>(hist, g1, WT2, dinv, xws);
    k_gather<<<(NN+3)/4, 256, 0, stream>>>(rowptr, ebuf, dinv, xws, b_g2, g2);

    // target gather + W_nbr + iga0
    k_target<<<NB, 128, 0, stream>>>(tgt, hist, g1, g2, Wnbr, bnbr, Wi0, bi0, iga0);

    // LSTM decoder (4 rows/block)
    k_lstm<<<NB/4, 512, 0, stream>>>(iga0, bh0, Wh0, Wi1, Wh1, bi1, bh1, hdec);

    // output projection
    k_out<<<(NB*25*2+255)/256, 256, 0, stream>>>(hdec, Wop, bop, out);
}

// Round 8
// 2542.824 us; speedup vs baseline: 1.0026x; 1.0026x over previous
//
#include <hip/hip_runtime.h>
#include <cstddef>

#define NN 50000
#define NE 1600000
#define NB 500
#define TT 16

__device__ __forceinline__ float leaky(float v){ return fmaxf(v, 0.1f*v); }

__device__ __forceinline__ float sigf(float x){
    float e = __expf(-fabsf(x));
    float p = __fdividef(1.0f, 1.0f + e);
    return x >= 0.0f ? p : 1.0f - p;
}
__device__ __forceinline__ float tanhf_(float x){
    float e = __expf(-2.0f*fabsf(x));
    float p = (1.0f - e) * __fdividef(1.0f, 1.0f + e);
    return x >= 0.0f ? p : -p;
}

// ---------------------------------------------------------------------------
// Fused emb + GRU(T=16) + dyn projection.
// Block = 256 threads = 4 waves, covers 64 node rows (lane = row).
// Wave w computes gate columns u in [16w, 16w+16) -> 3128 waves (~3/SIMD).
// h exchanged per step via u-major LDS hbuf[u][row] (bank=row%32, 2-way free).
// Weight addresses wave-uniform (u in SGPR) -> scalar broadcast loads.
// waves_per_eu(3,3): pin allocator to 168-VGPR budget. R7 evidence: with
// launch_bounds(256,3) the backend targeted 6 waves/EU -> 84 VGPRs -> spilled
// h[64]+e_[32] to scratch (WRITE_SIZE 43MB vs 13MB expected, occupancy 21.8%,
// VALUBusy 40%). Live set ~125 regs; 168 budget = zero spill; grid is 3
// blocks/CU anyway so >3 waves/EU buys nothing.
// ---------------------------------------------------------------------------
__attribute__((amdgpu_waves_per_eu(3,3)))
__global__ __launch_bounds__(256) void k_gru(
    const float* __restrict__ x,      // [NN,16,2]
    const float* __restrict__ W_ip,   // [32,2]
    const float* __restrict__ b_ip,   // [32]
    const float* __restrict__ Wi,     // [192,32]
    const float* __restrict__ Wh,     // [192,64]
    const float* __restrict__ bi,     // [192]
    const float* __restrict__ bh,     // [192]
    const float* __restrict__ Wdyn,   // [64,64]
    const float* __restrict__ bdyn,   // [64]
    float* __restrict__ hist)         // [NN,64]
{
    __shared__ float smem[4096 + 2048];       // hbuf[64][64] + xbuf[32][64]
    float* hbuf = smem;                       // hbuf[u*64 + row]
    float* xbuf = smem + 4096;                // xbuf[c*64 + row]
    float* obuf = smem;                       // phase-2 alias: obuf[j*65 + row]

    const int tid  = threadIdx.x;
    const int lane = tid & 63;                                  // row within block
    const int w    = __builtin_amdgcn_readfirstlane(tid >> 6);  // wave id -> SGPR
    const int rowbase = blockIdx.x * 64;
    const int u0 = w * 16;

    // stage x[rowbase..rowbase+64) into xbuf[c][r], coalesced
    {
        const size_t gbase = (size_t)rowbase * 32;
        const int r  = tid >> 2;
        const int c0 = (tid & 3) * 8;
        #pragma unroll
        for (int q = 0; q < 2; ++q) {
            size_t gi = gbase + (size_t)tid*8 + q*4;
            float4 v = (gi + 4 <= (size_t)NN*32) ? *(const float4*)&x[gi]
                                                 : make_float4(0.f,0.f,0.f,0.f);
            xbuf[(c0 + q*4 + 0)*64 + r] = v.x;
            xbuf[(c0 + q*4 + 1)*64 + r] = v.y;
            xbuf[(c0 + q*4 + 2)*64 + r] = v.z;
            xbuf[(c0 + q*4 + 3)*64 + r] = v.w;
        }
        #pragma unroll
        for (int q = 0; q < 16; ++q) hbuf[q*256 + tid] = 0.0f;
    }
    __syncthreads();

    float h[64];
    #pragma unroll
    for (int k = 0; k < 64; ++k) h[k] = 0.0f;

    for (int t = 0; t < TT; ++t) {
        const float x0 = xbuf[(2*t  )*64 + lane];
        const float x1 = xbuf[(2*t+1)*64 + lane];
        float e_[32];
        #pragma unroll
        for (int k = 0; k < 32; ++k)
            e_[k] = leaky(W_ip[2*k]*x0 + W_ip[2*k+1]*x1 + b_ip[k]);

        for (int j = 0; j < 16; ++j) {
            const int u = u0 + j;                       // wave-uniform
            float ir = bi[u], iz = bi[64+u], in_ = bi[128+u];
            #pragma unroll
            for (int k = 0; k < 32; ++k) {
                const float ek = e_[k];
                ir  += Wi[u*32       + k]*ek;
                iz  += Wi[(64+u)*32  + k]*ek;
                in_ += Wi[(128+u)*32 + k]*ek;
            }
            float hr = bh[u], hz = bh[64+u], hn = bh[128+u];
            #pragma unroll
            for (int k = 0; k < 64; ++k) {
                const float hk = h[k];
                hr += Wh[u*64       + k]*hk;
                hz += Wh[(64+u)*64  + k]*hk;
                hn += Wh[(128+u)*64 + k]*hk;
            }
            const float rg = sigf(ir + hr);
            const float zg = sigf(iz + hz);
            const float ng = tanhf_(in_ + rg*hn);
            const float hu = hbuf[u*64 + lane];          // old h[u]
            hbuf[u*64 + lane] = (1.0f - zg)*ng + zg*hu;  // only owner wave writes u
        }
        __syncthreads();
        #pragma unroll
        for (int k = 0; k < 64; ++k) h[k] = hbuf[k*64 + lane];
        __syncthreads();
    }

    // hist = leaky(leaky(h) @ Wdyn.T + bdyn), transposed store via obuf
    float lh[64];
    #pragma unroll
    for (int k = 0; k < 64; ++k) lh[k] = leaky(h[k]);

    for (int j = u0; j < u0 + 16; ++j) {                 // wave-uniform j
        float a = bdyn[j];
        #pragma unroll
        for (int k = 0; k < 64; ++k) a += Wdyn[j*64 + k]*lh[k];
        obuf[j*65 + lane] = leaky(a);
    }
    __syncthreads();
    #pragma unroll
    for (int i = 0; i < 16; ++i) {
        const int rr = u0 + i;
        const int grow = rowbase + rr;
        if (grow < NN) hist[(size_t)grow*64 + lane] = obuf[lane*65 + rr];
    }
}

// ---------------------------------------------------------------------------
__global__ __launch_bounds__(256) void k_deg(const int* __restrict__ dst,
                                             float* __restrict__ deg)
{
    int e = blockIdx.x*256 + threadIdx.x;
    if (e < NE) atomicAdd(&deg[dst[e]], 1.0f);
}

// single-block exclusive prefix scan of (int)deg -> rowptr, cursor
__global__ __launch_bounds__(1024) void k_scan(const float* __restrict__ deg,
                                               int* __restrict__ rowptr,
                                               int* __restrict__ cursor)
{
    __shared__ int sc[1024];
    const int tid = threadIdx.x;
    const int CH = 49;                          // 49*1024 >= NN
    const int base = tid*CH;
    int s = 0;
    for (int i = 0; i < CH; ++i) {
        int idx = base + i;
        if (idx < NN) s += (int)deg[idx];
    }
    sc[tid] = s;
    __syncthreads();
    for (int off = 1; off < 1024; off <<= 1) {
        int v = (tid >= off) ? sc[tid-off] : 0;
        __syncthreads();
        sc[tid] += v;
        __syncthreads();
    }
    int run = sc[tid] - s;                      // exclusive prefix
    for (int i = 0; i < CH; ++i) {
        int idx = base + i;
        if (idx < NN) {
            rowptr[idx] = run; cursor[idx] = run;
            run += (int)deg[idx];
        }
    }
    if (tid == 1023) rowptr[NN] = run;          // tid1023 chunk empty -> run = total
}

__global__ __launch_bounds__(256) void k_dinv(float* __restrict__ deg) // -> dinv
{
    int i = blockIdx.x*256 + threadIdx.x;
    if (i < NN) deg[i] = rsqrtf(deg[i] + 1.0f);
}

__global__ __launch_bounds__(256) void k_scatter(const int* __restrict__ src,
                                                 const int* __restrict__ dst,
                                                 int* __restrict__ cursor,
                                                 int* __restrict__ ebuf)
{
    int e = blockIdx.x*256 + threadIdx.x;
    if (e < NE) {
        int pos = atomicAdd(&cursor[dst[e]], 1);
        ebuf[pos] = src[e];
    }
}

__global__ __launch_bounds__(256) void k_transpose(const float* __restrict__ W,
                                                   float* __restrict__ WT, int R, int C)
{
    int i = blockIdx.x*256 + threadIdx.x;
    if (i < R*C) { int r = i / C, c = i % C; WT[c*R + r] = W[i]; }
}

// xws = (in @ W) * dinv[row]   (pre-scaled so the gather is a pure sum)
template <int K>
__global__ __launch_bounds__(256) void k_xw(
    const float* __restrict__ in0,
    const float* __restrict__ in1,   // second half when K=128
    const float* __restrict__ WT,    // [64][K]
    const float* __restrict__ dinv,
    float* __restrict__ xws)         // [NN,64]
{
    int row = blockIdx.x*256 + threadIdx.x;
    if (row >= NN) return;
    float in[K];
    #pragma unroll
    for (int k = 0; k < 64; k += 4) {
        float4 v = *(const float4*)&in0[(size_t)row*64 + k];
        in[k] = v.x; in[k+1] = v.y; in[k+2] = v.z; in[k+3] = v.w;
    }
    if (K == 128) {
        #pragma unroll
        for (int k = 0; k < 64; k += 4) {
            float4 v = *(const float4*)&in1[(size_t)row*64 + k];
            in[64+k] = v.x; in[64+k+1] = v.y; in[64+k+2] = v.z; in[64+k+3] = v.w;
        }
    }
    const float di = dinv[row];
    float* xr = xws + (size_t)row*64;
    for (int o = 0; o < 64; ++o) {
        float a = 0.0f;
        #pragma unroll
        for (int k = 0; k < K; ++k) a += WT[o*K + k]*in[k];
        xr[o] = a*di;
    }
}

// wave per dst node; lane = feature. out = dinv[d]*(sum xws[src] + xws[d]) + b
__global__ __launch_bounds__(256) void k_gather(
    const int* __restrict__ rowptr, const int* __restrict__ ebuf,
    const float* __restrict__ dinv, const float* __restrict__ xws,
    const float* __restrict__ bg, float* __restrict__ out)
{
    const int lane = threadIdx.x & 63;
    const int node = (blockIdx.x*256 + threadIdx.x) >> 6;
    if (node >= NN) return;
    const int s0 = rowptr[node], s1 = rowptr[node+1];
    float a0 = 0.f, a1 = 0.f, a2 = 0.f, a3 = 0.f;
    int j = s0;
    for (; j + 4 <= s1; j += 4) {
        const int e0 = ebuf[j], e1 = ebuf[j+1], e2 = ebuf[j+2], e3 = ebuf[j+3];
        a0 += xws[(size_t)e0*64 + lane];
        a1 += xws[(size_t)e1*64 + lane];
        a2 += xws[(size_t)e2*64 + lane];
        a3 += xws[(size_t)e3*64 + lane];
    }
    for (; j < s1; ++j) a0 += xws[(size_t)ebuf[j]*64 + lane];
    const float acc = ((a0+a1) + (a2+a3)) + xws[(size_t)node*64 + lane];
    out[(size_t)node*64 + lane] = dinv[node]*acc + bg[lane];
}

// ---------------------------------------------------------------------------
__global__ __launch_bounds__(128) void k_target(
    const int* __restrict__ tgt,
    const float* __restrict__ hist, const float* __restrict__ g1,
    const float* __restrict__ g2,
    const float* __restrict__ Wnbr, const float* __restrict__ bnbr, // [64,128],[64]
    const float* __restrict__ Wi0,  const float* __restrict__ bi0,  // [512,128],[512]
    float* __restrict__ iga0)                                       // [NB,512]
{
    __shared__ float feat[128];
    __shared__ float enc[128];
    const int b = blockIdx.x, t = threadIdx.x;
    const int n = tgt[b];
    if (t < 64) {
        feat[t]    = g1[(size_t)n*64 + t];
        feat[64+t] = g2[(size_t)n*64 + t];
        enc[t]     = hist[(size_t)n*64 + t];
    }
    __syncthreads();
    if (t < 64) {
        float a = bnbr[t];
        #pragma unroll 16
        for (int k = 0; k < 128; ++k) a += Wnbr[t*128 + k]*feat[k];
        enc[64+t] = leaky(a);
    }
    __syncthreads();
    #pragma unroll
    for (int rep = 0; rep < 4; ++rep) {
        const int o = t + rep*128;
        float a = bi0[o];
        #pragma unroll 16
        for (int k = 0; k < 128; ++k) a += Wi0[o*128 + k]*enc[k];
        iga0[(size_t)b*512 + o] = a;
    }
}

// ---------------------------------------------------------------------------
// 2-layer LSTM decoder, 25 steps. 125 blocks x 512 threads, 4 rows/block.
// Per-block weight stream = 768KB/step from L2 regardless of rows, so fewer
// blocks => less L2 traffic: 125 x 19.2MB = 2.4GB (~70us floor) vs 4.8GB at
// 250 blocks. Per-row arithmetic identical to the 2-row version (same dot
// expressions and order) -- only the thread->row mapping changed.
// ---------------------------------------------------------------------------
__global__ __launch_bounds__(512) void k_lstm(
    const float* __restrict__ iga0,  // [NB,512] = enc@Wi0.T + bi0
    const float* __restrict__ bh0,   // [512]
    const float* __restrict__ Wh0,   // [512,128]
    const float* __restrict__ Wi1,   // [512,128]
    const float* __restrict__ Wh1,   // [512,128]
    const float* __restrict__ bi1, const float* __restrict__ bh1, // [512]
    float* __restrict__ hdec)        // [NB,25,128]
{
    __shared__ float h0[4][128], h1[4][128], g[4][512];
    const int t  = threadIdx.x;
    const int b0 = blockIdx.x*4;
    const int r  = t >> 7;          // row updated by this thread (0..3)
    const int u  = t & 127;         // unit within row

    if (t < 128) {
        #pragma unroll
        for (int q = 0; q < 4; ++q) { h0[q][t] = 0.f; h1[q][t] = 0.f; }
    }
    float c0 = 0.f, c1 = 0.f;       // cell state of (r,u) for this thread
    float ig[4];
    #pragma unroll
    for (int q = 0; q < 4; ++q)
        ig[q] = iga0[(size_t)(b0+q)*512 + t] + bh0[t];
    const float bL1 = bi1[t] + bh1[t];
    __syncthreads();

    for (int s = 0; s < 25; ++s) {
        // ---- layer 0 gates: g[q] = ig[q] + h0[q] @ Wh0.T ----
        float a0 = ig[0], a1 = ig[1], a2 = ig[2], a3 = ig[3];
        #pragma unroll 4
        for (int k = 0; k < 128; k += 4) {
            const float4 w  = *(const float4*)&Wh0[(size_t)t*128 + k];
            const float4 p0 = *(const float4*)&h0[0][k];
            const float4 p1 = *(const float4*)&h0[1][k];
            const float4 p2 = *(const float4*)&h0[2][k];
            const float4 p3 = *(const float4*)&h0[3][k];
            a0 += w.x*p0.x + w.y*p0.y + w.z*p0.z + w.w*p0.w;
            a1 += w.x*p1.x + w.y*p1.y + w.z*p1.z + w.w*p1.w;
            a2 += w.x*p2.x + w.y*p2.y + w.z*p2.z + w.w*p2.w;
            a3 += w.x*p3.x + w.y*p3.y + w.z*p3.z + w.w*p3.w;
        }
        g[0][t] = a0; g[1][t] = a1; g[2][t] = a2; g[3][t] = a3;
        __syncthreads();
        {   // update layer 0: all 512 threads, thread -> (r,u)
            const float i_ = sigf(g[r][u]);
            const float f_ = sigf(g[r][128+u]);
            const float g_ = tanhf_(g[r][256+u]);
            const float o_ = sigf(g[r][384+u]);
            c0 = f_*c0 + i_*g_;
            h0[r][u] = o_*tanhf_(c0);
        }
        __syncthreads();
        // ---- layer 1 gates: g[q] = bL1 + h0[q] @ Wi1.T + h1[q] @ Wh1.T ----
        float b0a = bL1, b1a = bL1, b2a = bL1, b3a = bL1;
        #pragma unroll 4
        for (int k = 0; k < 128; k += 4) {
            const float4 wi = *(const float4*)&Wi1[(size_t)t*128 + k];
            const float4 wh = *(const float4*)&Wh1[(size_t)t*128 + k];
            const float4 q0 = *(const float4*)&h0[0][k];
            const float4 q1 = *(const float4*)&h0[1][k];
            const float4 q2 = *(const float4*)&h0[2][k];
            const float4 q3 = *(const float4*)&h0[3][k];
            const float4 r0 = *(const float4*)&h1[0][k];
            const float4 r1 = *(const float4*)&h1[1][k];
            const float4 r2 = *(const float4*)&h1[2][k];
            const float4 r3 = *(const float4*)&h1[3][k];
            b0a += wi.x*q0.x + wi.y*q0.y + wi.z*q0.z + wi.w*q0.w
                 + wh.x*r0.x + wh.y*r0.y + wh.z*r0.z + wh.w*r0.w;
            b1a += wi.x*q1.x + wi.y*q1.y + wi.z*q1.z + wi.w*q1.w
                 + wh.x*r1.x + wh.y*r1.y + wh.z*r1.z + wh.w*r1.w;
            b2a += wi.x*q2.x + wi.y*q2.y + wi.z*q2.z + wi.w*q2.w
                 + wh.x*r2.x + wh.y*r2.y + wh.z*r2.z + wh.w*r2.w;
            b3a += wi.x*q3.x + wi.y*q3.y + wi.z*q3.z + wi.w*q3.w
                 + wh.x*r3.x + wh.y*r3.y + wh.z*r3.z + wh.w*r3.w;
        }
        g[0][t] = b0a; g[1][t] = b1a; g[2][t] = b2a; g[3][t] = b3a;
        __syncthreads();
        {   // update layer 1 + store
            const float i_ = sigf(g[r][u]);
            const float f_ = sigf(g[r][128+u]);
            const float g_ = tanhf_(g[r][256+u]);
            const float o_ = sigf(g[r][384+u]);
            c1 = f_*c1 + i_*g_;
            const float hv = o_*tanhf_(c1);
            h1[r][u] = hv;
            hdec[((size_t)(b0+r)*25 + s)*128 + u] = hv;
        }
        __syncthreads();
    }
}

__global__ __launch_bounds__(256) void k_out(
    const float* __restrict__ hdec, const float* __restrict__ Wop,
    const float* __restrict__ bop, float* __restrict__ out)
{
    const int i = blockIdx.x*256 + threadIdx.x;
    if (i >= NB*25*2) return;
    const int o = i & 1, bs = i >> 1;
    float a = bop[o];
    const float* h = hdec + (size_t)bs*128;
    #pragma unroll 16
    for (int k = 0; k < 128; ++k) a += Wop[o*128 + k]*h[k];
    out[i] = a;
}

// ---------------------------------------------------------------------------
extern "C" void kernel_launch(void* const* d_in, const int* in_sizes, int n_in,
                              void* d_out, int out_size, void* d_ws, size_t ws_size,
                              hipStream_t stream)
{
    const float* x     = (const float*)d_in[0];
    const float* W_ip  = (const float*)d_in[1];
    const float* b_ip  = (const float*)d_in[2];
    const float* gWi   = (const float*)d_in[3];
    const float* gWh   = (const float*)d_in[4];
    const float* gbi   = (const float*)d_in[5];
    const float* gbh   = (const float*)d_in[6];
    const float* Wdyn  = (const float*)d_in[7];
    const float* bdyn  = (const float*)d_in[8];
    const float* W_g1  = (const float*)d_in[9];
    const float* b_g1  = (const float*)d_in[10];
    const float* W_g2  = (const float*)d_in[11];
    const float* b_g2  = (const float*)d_in[12];
    const float* Wnbr  = (const float*)d_in[13];
    const float* bnbr  = (const float*)d_in[14];
    const float* Wi0   = (const float*)d_in[15];
    const float* Wh0   = (const float*)d_in[16];
    const float* bi0   = (const float*)d_in[17];
    const float* bh0   = (const float*)d_in[18];
    const float* Wi1   = (const float*)d_in[19];
    const float* Wh1   = (const float*)d_in[20];
    const float* bi1   = (const float*)d_in[21];
    const float* bh1   = (const float*)d_in[22];
    const float* Wop   = (const float*)d_in[23];
    const float* bop   = (const float*)d_in[24];
    const int*   eidx  = (const int*)d_in[25];
    const int*   tgt   = (const int*)d_in[26];
    const int* esrc = eidx;
    const int* edst = eidx + NE;

    float* ws   = (float*)d_ws;
    float* hist = ws;                               // 3.2M floats
    float* xws  = ws + 3200000;                     // 3.2M
    float* g1   = ws + 6400000;                     // 3.2M
    float* g2   = ws + 9600000;                     // 3.2M
    float* dinv = ws + 12800000;                    // 50K (deg -> dinv in place)
    int* rowptr = (int*)(ws + 12860000);            // 50001
    int* cursor = (int*)(ws + 12920000);            // 50000
    int* ebuf   = (int*)(ws + 12980000);            // 1.6M
    float* WT1  = ws + 14580000;                    // 4096
    float* WT2  = ws + 14590000;                    // 8192
    float* iga0 = ws + 14600000;                    // 256K
    float* hdec = xws;                              // reuse: xws dead after gather #2
    float* out  = (float*)d_out;

    hipMemsetAsync(dinv, 0, NN*sizeof(float), stream);
    k_transpose<<<16, 256, 0, stream>>>(W_g1, WT1, 64, 64);
    k_transpose<<<32, 256, 0, stream>>>(W_g2, WT2, 128, 64);
    k_deg<<<(NE+255)/256, 256, 0, stream>>>(edst, dinv);
    k_scan<<<1, 1024, 0, stream>>>(dinv, rowptr, cursor);
    k_dinv<<<(NN+255)/256, 256, 0, stream>>>(dinv);
    k_scatter<<<(NE+255)/256, 256, 0, stream>>>(esrc, edst, cursor, ebuf);

    // GRU encoder
    k_gru<<<(NN+63)/64, 256, 0, stream>>>(x, W_ip, b_ip, gWi, gWh, gbi, gbh,
                                          Wdyn, bdyn, hist);

    // GCN layer 1
    k_xw<64><<<(NN+255)/256, 256, 0, stream>>>(hist, nullptr, WT1, dinv, xws);
    k_gather<<<(NN+3)/4, 256, 0, stream>>>(rowptr, ebuf, dinv, xws, b_g1, g1);
    // GCN layer 2 (input concat(hist, g1))
    k_xw<128><<<(NN+255)/256, 256, 0, stream>>>(hist, g1, WT2, dinv, xws);
    k_gather<<<(NN+3)/4, 256, 0, stream>>>(rowptr, ebuf, dinv, xws, b_g2, g2);

    // target gather + W_nbr + iga0
    k_target<<<NB, 128, 0, stream>>>(tgt, hist, g1, g2, Wnbr, bnbr, Wi0, bi0, iga0);

    // LSTM decoder (4 rows/block)
    k_lstm<<<NB/4, 512, 0, stream>>>(iga0, bh0, Wh0, Wi1, Wh1, bi1, bh1, hdec);

    // output projection
    k_out<<<(NB*25*2+255)/256, 256, 0, stream>>>(hdec, Wop, bop, out);
}

// Round 9
// 2318.842 us; speedup vs baseline: 1.0994x; 1.0966x over previous
//
#include <hip/hip_runtime.h>
#include <cstddef>

#define NN 50000
#define NE 1600000
#define NB 500
#define TT 16

__device__ __forceinline__ float leaky(float v){ return fmaxf(v, 0.1f*v); }

__device__ __forceinline__ float sigf(float x){
    float e = __expf(-fabsf(x));
    float p = __fdividef(1.0f, 1.0f + e);
    return x >= 0.0f ? p : 1.0f - p;
}
__device__ __forceinline__ float tanhf_(float x){
    float e = __expf(-2.0f*fabsf(x));
    float p = (1.0f - e) * __fdividef(1.0f, 1.0f + e);
    return x >= 0.0f ? p : -p;
}

// ---------------------------------------------------------------------------
// Fused emb + GRU(T=16) + dyn projection.
// Block = 256 threads = 4 waves, covers 64 node rows (lane = row).
// Wave w computes gate columns u in [16w,16w+16).
// R8 post-mortem: live set h[64]+e_[32]+acc ~110 > 84-reg budget the backend
// insists on -> ~30 regs spilled to scratch (WRITE_SIZE 43MB, occupancy 21.8%,
// VALUBusy 40%, 1300us). Structural fix: e_ lives in LDS ebuf[64][36] (144B
// rows: b128-aligned, bank=(4(lane+m))%32 uniform -> conflict-optimal).
// Each wave computes its 8-float e-chunk (emb compute /4), j-loop re-reads
// 8x ds_read_b128. New live set ~80 <= 84 -> no spill regardless of budget.
// ebuf/hbuf share one __shared__ array so alias analysis can't hoist the
// e-reads back into registers (hbuf writes in-loop may alias).
// ---------------------------------------------------------------------------
__attribute__((amdgpu_waves_per_eu(3,3)))
__global__ __launch_bounds__(256) void k_gru(
    const float* __restrict__ x,      // [NN,16,2]
    const float* __restrict__ W_ip,   // [32,2]
    const float* __restrict__ b_ip,   // [32]
    const float* __restrict__ Wi,     // [192,32]
    const float* __restrict__ Wh,     // [192,64]
    const float* __restrict__ bi,     // [192]
    const float* __restrict__ bh,     // [192]
    const float* __restrict__ Wdyn,   // [64,64]
    const float* __restrict__ bdyn,   // [64]
    float* __restrict__ hist)         // [NN,64]
{
    __shared__ float smem[4096 + 2304 + 2048];  // hbuf[64][64] + ebuf[64][36] + xbuf[32][64]
    float* hbuf = smem;                         // hbuf[u*64 + row], u-major
    float* ebuf = smem + 4096;                  // ebuf[row*36 + k], 144B rows
    float* xbuf = smem + 4096 + 2304;           // xbuf[c*64 + row]
    float* obuf = smem;                         // phase-2 alias: obuf[j*65 + row] (4158 < 6400)

    const int tid  = threadIdx.x;
    const int lane = tid & 63;                                  // row within block
    const int w    = __builtin_amdgcn_readfirstlane(tid >> 6);  // wave id -> SGPR
    const int rowbase = blockIdx.x * 64;
    const int u0 = w * 16;                                      // gate-column base
    const int k0 = w * 8;                                       // e-chunk base

    // stage x[rowbase..rowbase+64) into xbuf[c][r], coalesced
    {
        const size_t gbase = (size_t)rowbase * 32;
        const int r  = tid >> 2;
        const int c0 = (tid & 3) * 8;
        #pragma unroll
        for (int q = 0; q < 2; ++q) {
            size_t gi = gbase + (size_t)tid*8 + q*4;
            float4 v = (gi + 4 <= (size_t)NN*32) ? *(const float4*)&x[gi]
                                                 : make_float4(0.f,0.f,0.f,0.f);
            xbuf[(c0 + q*4 + 0)*64 + r] = v.x;
            xbuf[(c0 + q*4 + 1)*64 + r] = v.y;
            xbuf[(c0 + q*4 + 2)*64 + r] = v.z;
            xbuf[(c0 + q*4 + 3)*64 + r] = v.w;
        }
        #pragma unroll
        for (int q = 0; q < 16; ++q) hbuf[q*256 + tid] = 0.0f;
    }
    __syncthreads();

    float h[64];
    #pragma unroll
    for (int k = 0; k < 64; ++k) h[k] = 0.0f;

    for (int t = 0; t < TT; ++t) {
        // --- emb: wave w computes e[k0..k0+8) for row=lane, to LDS ---
        {
            const float x0 = xbuf[(2*t  )*64 + lane];
            const float x1 = xbuf[(2*t+1)*64 + lane];
            float ev[8];
            #pragma unroll
            for (int q = 0; q < 8; ++q) {
                const int k = k0 + q;
                ev[q] = leaky(W_ip[2*k]*x0 + W_ip[2*k+1]*x1 + b_ip[k]);
            }
            *(float4*)&ebuf[lane*36 + k0]     = make_float4(ev[0],ev[1],ev[2],ev[3]);
            *(float4*)&ebuf[lane*36 + k0 + 4] = make_float4(ev[4],ev[5],ev[6],ev[7]);
        }
        __syncthreads();

        for (int j = 0; j < 16; ++j) {
            const int u = u0 + j;                       // wave-uniform
            float ir = bi[u], iz = bi[64+u], in_ = bi[128+u];
            #pragma unroll
            for (int m = 0; m < 8; ++m) {               // e via LDS b128 (not hoistable)
                const float4 e4 = *(const float4*)&ebuf[lane*36 + m*4];
                const int kb = m*4;
                ir  += Wi[u*32+kb]*e4.x       + Wi[u*32+kb+1]*e4.y
                     + Wi[u*32+kb+2]*e4.z     + Wi[u*32+kb+3]*e4.w;
                iz  += Wi[(64+u)*32+kb]*e4.x  + Wi[(64+u)*32+kb+1]*e4.y
                     + Wi[(64+u)*32+kb+2]*e4.z+ Wi[(64+u)*32+kb+3]*e4.w;
                in_ += Wi[(128+u)*32+kb]*e4.x + Wi[(128+u)*32+kb+1]*e4.y
                     + Wi[(128+u)*32+kb+2]*e4.z+Wi[(128+u)*32+kb+3]*e4.w;
            }
            float hr = bh[u], hz = bh[64+u], hn = bh[128+u];
            #pragma unroll
            for (int k = 0; k < 64; ++k) {
                const float hk = h[k];
                hr += Wh[u*64       + k]*hk;
                hz += Wh[(64+u)*64  + k]*hk;
                hn += Wh[(128+u)*64 + k]*hk;
            }
            const float rg = sigf(ir + hr);
            const float zg = sigf(iz + hz);
            const float ng = tanhf_(in_ + rg*hn);
            const float hu = hbuf[u*64 + lane];          // old h[u]
            hbuf[u*64 + lane] = (1.0f - zg)*ng + zg*hu;  // only owner wave writes u
        }
        __syncthreads();
        #pragma unroll
        for (int k = 0; k < 64; ++k) h[k] = hbuf[k*64 + lane];
        __syncthreads();
    }

    // hist = leaky(leaky(h) @ Wdyn.T + bdyn), transposed store via obuf
    float lh[64];
    #pragma unroll
    for (int k = 0; k < 64; ++k) lh[k] = leaky(h[k]);

    for (int j = u0; j < u0 + 16; ++j) {                 // wave-uniform j
        float a = bdyn[j];
        #pragma unroll
        for (int k = 0; k < 64; ++k) a += Wdyn[j*64 + k]*lh[k];
        obuf[j*65 + lane] = leaky(a);
    }
    __syncthreads();
    #pragma unroll
    for (int i = 0; i < 16; ++i) {
        const int rr = u0 + i;
        const int grow = rowbase + rr;
        if (grow < NN) hist[(size_t)grow*64 + lane] = obuf[lane*65 + rr];
    }
}

// ---------------------------------------------------------------------------
__global__ __launch_bounds__(256) void k_deg(const int* __restrict__ dst,
                                             float* __restrict__ deg)
{
    int e = blockIdx.x*256 + threadIdx.x;
    if (e < NE) atomicAdd(&deg[dst[e]], 1.0f);
}

// single-block exclusive prefix scan of (int)deg -> rowptr, cursor
__global__ __launch_bounds__(1024) void k_scan(const float* __restrict__ deg,
                                               int* __restrict__ rowptr,
                                               int* __restrict__ cursor)
{
    __shared__ int sc[1024];
    const int tid = threadIdx.x;
    const int CH = 49;                          // 49*1024 >= NN
    const int base = tid*CH;
    int s = 0;
    for (int i = 0; i < CH; ++i) {
        int idx = base + i;
        if (idx < NN) s += (int)deg[idx];
    }
    sc[tid] = s;
    __syncthreads();
    for (int off = 1; off < 1024; off <<= 1) {
        int v = (tid >= off) ? sc[tid-off] : 0;
        __syncthreads();
        sc[tid] += v;
        __syncthreads();
    }
    int run = sc[tid] - s;                      // exclusive prefix
    for (int i = 0; i < CH; ++i) {
        int idx = base + i;
        if (idx < NN) {
            rowptr[idx] = run; cursor[idx] = run;
            run += (int)deg[idx];
        }
    }
    if (tid == 1023) rowptr[NN] = run;          // tid1023 chunk empty -> run = total
}

__global__ __launch_bounds__(256) void k_dinv(float* __restrict__ deg) // -> dinv
{
    int i = blockIdx.x*256 + threadIdx.x;
    if (i < NN) deg[i] = rsqrtf(deg[i] + 1.0f);
}

__global__ __launch_bounds__(256) void k_scatter(const int* __restrict__ src,
                                                 const int* __restrict__ dst,
                                                 int* __restrict__ cursor,
                                                 int* __restrict__ ebuf)
{
    int e = blockIdx.x*256 + threadIdx.x;
    if (e < NE) {
        int pos = atomicAdd(&cursor[dst[e]], 1);
        ebuf[pos] = src[e];
    }
}

__global__ __launch_bounds__(256) void k_transpose(const float* __restrict__ W,
                                                   float* __restrict__ WT, int R, int C)
{
    int i = blockIdx.x*256 + threadIdx.x;
    if (i < R*C) { int r = i / C, c = i % C; WT[c*R + r] = W[i]; }
}

// xws = (in @ W) * dinv[row]   (pre-scaled so the gather is a pure sum)
template <int K>
__global__ __launch_bounds__(256) void k_xw(
    const float* __restrict__ in0,
    const float* __restrict__ in1,   // second half when K=128
    const float* __restrict__ WT,    // [64][K]
    const float* __restrict__ dinv,
    float* __restrict__ xws)         // [NN,64]
{
    int row = blockIdx.x*256 + threadIdx.x;
    if (row >= NN) return;
    float in[K];
    #pragma unroll
    for (int k = 0; k < 64; k += 4) {
        float4 v = *(const float4*)&in0[(size_t)row*64 + k];
        in[k] = v.x; in[k+1] = v.y; in[k+2] = v.z; in[k+3] = v.w;
    }
    if (K == 128) {
        #pragma unroll
        for (int k = 0; k < 64; k += 4) {
            float4 v = *(const float4*)&in1[(size_t)row*64 + k];
            in[64+k] = v.x; in[64+k+1] = v.y; in[64+k+2] = v.z; in[64+k+3] = v.w;
        }
    }
    const float di = dinv[row];
    float* xr = xws + (size_t)row*64;
    for (int o = 0; o < 64; ++o) {
        float a = 0.0f;
        #pragma unroll
        for (int k = 0; k < K; ++k) a += WT[o*K + k]*in[k];
        xr[o] = a*di;
    }
}

// wave per dst node; lane = feature. out = dinv[d]*(sum xws[src] + xws[d]) + b
__global__ __launch_bounds__(256) void k_gather(
    const int* __restrict__ rowptr, const int* __restrict__ ebuf,
    const float* __restrict__ dinv, const float* __restrict__ xws,
    const float* __restrict__ bg, float* __restrict__ out)
{
    const int lane = threadIdx.x & 63;
    const int node = (blockIdx.x*256 + threadIdx.x) >> 6;
    if (node >= NN) return;
    const int s0 = rowptr[node], s1 = rowptr[node+1];
    float a0 = 0.f, a1 = 0.f, a2 = 0.f, a3 = 0.f;
    int j = s0;
    for (; j + 4 <= s1; j += 4) {
        const int e0 = ebuf[j], e1 = ebuf[j+1], e2 = ebuf[j+2], e3 = ebuf[j+3];
        a0 += xws[(size_t)e0*64 + lane];
        a1 += xws[(size_t)e1*64 + lane];
        a2 += xws[(size_t)e2*64 + lane];
        a3 += xws[(size_t)e3*64 + lane];
    }
    for (; j < s1; ++j) a0 += xws[(size_t)ebuf[j]*64 + lane];
    const float acc = ((a0+a1) + (a2+a3)) + xws[(size_t)node*64 + lane];
    out[(size_t)node*64 + lane] = dinv[node]*acc + bg[lane];
}

// ---------------------------------------------------------------------------
__global__ __launch_bounds__(128) void k_target(
    const int* __restrict__ tgt,
    const float* __restrict__ hist, const float* __restrict__ g1,
    const float* __restrict__ g2,
    const float* __restrict__ Wnbr, const float* __restrict__ bnbr, // [64,128],[64]
    const float* __restrict__ Wi0,  const float* __restrict__ bi0,  // [512,128],[512]
    float* __restrict__ iga0)                                       // [NB,512]
{
    __shared__ float feat[128];
    __shared__ float enc[128];
    const int b = blockIdx.x, t = threadIdx.x;
    const int n = tgt[b];
    if (t < 64) {
        feat[t]    = g1[(size_t)n*64 + t];
        feat[64+t] = g2[(size_t)n*64 + t];
        enc[t]     = hist[(size_t)n*64 + t];
    }
    __syncthreads();
    if (t < 64) {
        float a = bnbr[t];
        #pragma unroll 16
        for (int k = 0; k < 128; ++k) a += Wnbr[t*128 + k]*feat[k];
        enc[64+t] = leaky(a);
    }
    __syncthreads();
    #pragma unroll
    for (int rep = 0; rep < 4; ++rep) {
        const int o = t + rep*128;
        float a = bi0[o];
        #pragma unroll 16
        for (int k = 0; k < 128; ++k) a += Wi0[o*128 + k]*enc[k];
        iga0[(size_t)b*512 + o] = a;
    }
}

// ---------------------------------------------------------------------------
// 2-layer LSTM decoder, 25 steps. 125 blocks x 512 threads, 4 rows/block.
// Per-block weight stream = 768KB/step from L2 regardless of rows, so fewer
// blocks => less L2 traffic. (R8 note: the lone 40.9ms k_lstm dispatch in the
// rocprof table is a replay outlier -- all other k_lstm dispatches fall below
// the 1297us top-5 cutoff and the 2542us timed total excludes a 40ms kernel.)
// ---------------------------------------------------------------------------
__global__ __launch_bounds__(512) void k_lstm(
    const float* __restrict__ iga0,  // [NB,512] = enc@Wi0.T + bi0
    const float* __restrict__ bh0,   // [512]
    const float* __restrict__ Wh0,   // [512,128]
    const float* __restrict__ Wi1,   // [512,128]
    const float* __restrict__ Wh1,   // [512,128]
    const float* __restrict__ bi1, const float* __restrict__ bh1, // [512]
    float* __restrict__ hdec)        // [NB,25,128]
{
    __shared__ float h0[4][128], h1[4][128], g[4][512];
    const int t  = threadIdx.x;
    const int b0 = blockIdx.x*4;
    const int r  = t >> 7;          // row updated by this thread (0..3)
    const int u  = t & 127;         // unit within row

    if (t < 128) {
        #pragma unroll
        for (int q = 0; q < 4; ++q) { h0[q][t] = 0.f; h1[q][t] = 0.f; }
    }
    float c0 = 0.f, c1 = 0.f;       // cell state of (r,u) for this thread
    float ig[4];
    #pragma unroll
    for (int q = 0; q < 4; ++q)
        ig[q] = iga0[(size_t)(b0+q)*512 + t] + bh0[t];
    const float bL1 = bi1[t] + bh1[t];
    __syncthreads();

    for (int s = 0; s < 25; ++s) {
        // ---- layer 0 gates: g[q] = ig[q] + h0[q] @ Wh0.T ----
        float a0 = ig[0], a1 = ig[1], a2 = ig[2], a3 = ig[3];
        #pragma unroll 4
        for (int k = 0; k < 128; k += 4) {
            const float4 w  = *(const float4*)&Wh0[(size_t)t*128 + k];
            const float4 p0 = *(const float4*)&h0[0][k];
            const float4 p1 = *(const float4*)&h0[1][k];
            const float4 p2 = *(const float4*)&h0[2][k];
            const float4 p3 = *(const float4*)&h0[3][k];
            a0 += w.x*p0.x + w.y*p0.y + w.z*p0.z + w.w*p0.w;
            a1 += w.x*p1.x + w.y*p1.y + w.z*p1.z + w.w*p1.w;
            a2 += w.x*p2.x + w.y*p2.y + w.z*p2.z + w.w*p2.w;
            a3 += w.x*p3.x + w.y*p3.y + w.z*p3.z + w.w*p3.w;
        }
        g[0][t] = a0; g[1][t] = a1; g[2][t] = a2; g[3][t] = a3;
        __syncthreads();
        {   // update layer 0: all 512 threads, thread -> (r,u)
            const float i_ = sigf(g[r][u]);
            const float f_ = sigf(g[r][128+u]);
            const float g_ = tanhf_(g[r][256+u]);
            const float o_ = sigf(g[r][384+u]);
            c0 = f_*c0 + i_*g_;
            h0[r][u] = o_*tanhf_(c0);
        }
        __syncthreads();
        // ---- layer 1 gates: g[q] = bL1 + h0[q] @ Wi1.T + h1[q] @ Wh1.T ----
        float b0a = bL1, b1a = bL1, b2a = bL1, b3a = bL1;
        #pragma unroll 4
        for (int k = 0; k < 128; k += 4) {
            const float4 wi = *(const float4*)&Wi1[(size_t)t*128 + k];
            const float4 wh = *(const float4*)&Wh1[(size_t)t*128 + k];
            const float4 q0 = *(const float4*)&h0[0][k];
            const float4 q1 = *(const float4*)&h0[1][k];
            const float4 q2 = *(const float4*)&h0[2][k];
            const float4 q3 = *(const float4*)&h0[3][k];
            const float4 r0 = *(const float4*)&h1[0][k];
            const float4 r1 = *(const float4*)&h1[1][k];
            const float4 r2 = *(const float4*)&h1[2][k];
            const float4 r3 = *(const float4*)&h1[3][k];
            b0a += wi.x*q0.x + wi.y*q0.y + wi.z*q0.z + wi.w*q0.w
                 + wh.x*r0.x + wh.y*r0.y + wh.z*r0.z + wh.w*r0.w;
            b1a += wi.x*q1.x + wi.y*q1.y + wi.z*q1.z + wi.w*q1.w
                 + wh.x*r1.x + wh.y*r1.y + wh.z*r1.z + wh.w*r1.w;
            b2a += wi.x*q2.x + wi.y*q2.y + wi.z*q2.z + wi.w*q2.w
                 + wh.x*r2.x + wh.y*r2.y + wh.z*r2.z + wh.w*r2.w;
            b3a += wi.x*q3.x + wi.y*q3.y + wi.z*q3.z + wi.w*q3.w
                 + wh.x*r3.x + wh.y*r3.y + wh.z*r3.z + wh.w*r3.w;
        }
        g[0][t] = b0a; g[1][t] = b1a; g[2][t] = b2a; g[3][t] = b3a;
        __syncthreads();
        {   // update layer 1 + store
            const float i_ = sigf(g[r][u]);
            const float f_ = sigf(g[r][128+u]);
            const float g_ = tanhf_(g[r][256+u]);
            const float o_ = sigf(g[r][384+u]);
            c1 = f_*c1 + i_*g_;
            const float hv = o_*tanhf_(c1);
            h1[r][u] = hv;
            hdec[((size_t)(b0+r)*25 + s)*128 + u] = hv;
        }
        __syncthreads();
    }
}

__global__ __launch_bounds__(256) void k_out(
    const float* __restrict__ hdec, const float* __restrict__ Wop,
    const float* __restrict__ bop, float* __restrict__ out)
{
    const int i = blockIdx.x*256 + threadIdx.x;
    if (i >= NB*25*2) return;
    const int o = i & 1, bs = i >> 1;
    float a = bop[o];
    const float* h = hdec + (size_t)bs*128;
    #pragma unroll 16
    for (int k = 0; k < 128; ++k) a += Wop[o*128 + k]*h[k];
    out[i] = a;
}

// ---------------------------------------------------------------------------
extern "C" void kernel_launch(void* const* d_in, const int* in_sizes, int n_in,
                              void* d_out, int out_size, void* d_ws, size_t ws_size,
                              hipStream_t stream)
{
    const float* x     = (const float*)d_in[0];
    const float* W_ip  = (const float*)d_in[1];
    const float* b_ip  = (const float*)d_in[2];
    const float* gWi   = (const float*)d_in[3];
    const float* gWh   = (const float*)d_in[4];
    const float* gbi   = (const float*)d_in[5];
    const float* gbh   = (const float*)d_in[6];
    const float* Wdyn  = (const float*)d_in[7];
    const float* bdyn  = (const float*)d_in[8];
    const float* W_g1  = (const float*)d_in[9];
    const float* b_g1  = (const float*)d_in[10];
    const float* W_g2  = (const float*)d_in[11];
    const float* b_g2  = (const float*)d_in[12];
    const float* Wnbr  = (const float*)d_in[13];
    const float* bnbr  = (const float*)d_in[14];
    const float* Wi0   = (const float*)d_in[15];
    const float* Wh0   = (const float*)d_in[16];
    const float* bi0   = (const float*)d_in[17];
    const float* bh0   = (const float*)d_in[18];
    const float* Wi1   = (const float*)d_in[19];
    const float* Wh1   = (const float*)d_in[20];
    const float* bi1   = (const float*)d_in[21];
    const float* bh1   = (const float*)d_in[22];
    const float* Wop   = (const float*)d_in[23];
    const float* bop   = (const float*)d_in[24];
    const int*   eidx  = (const int*)d_in[25];
    const int*   tgt   = (const int*)d_in[26];
    const int* esrc = eidx;
    const int* edst = eidx + NE;

    float* ws   = (float*)d_ws;
    float* hist = ws;                               // 3.2M floats
    float* xws  = ws + 3200000;                     // 3.2M
    float* g1   = ws + 6400000;                     // 3.2M
    float* g2   = ws + 9600000;                     // 3.2M
    float* dinv = ws + 12800000;                    // 50K (deg -> dinv in place)
    int* rowptr = (int*)(ws + 12860000);            // 50001
    int* cursor = (int*)(ws + 12920000);            // 50000
    int* ebuf   = (int*)(ws + 12980000);            // 1.6M
    float* WT1  = ws + 14580000;                    // 4096
    float* WT2  = ws + 14590000;                    // 8192
    float* iga0 = ws + 14600000;                    // 256K
    float* hdec = xws;                              // reuse: xws dead after gather #2
    float* out  = (float*)d_out;

    hipMemsetAsync(dinv, 0, NN*sizeof(float), stream);
    k_transpose<<<16, 256, 0, stream>>>(W_g1, WT1, 64, 64);
    k_transpose<<<32, 256, 0, stream>>>(W_g2, WT2, 128, 64);
    k_deg<<<(NE+255)/256, 256, 0, stream>>>(edst, dinv);
    k_scan<<<1, 1024, 0, stream>>>(dinv, rowptr, cursor);
    k_dinv<<<(NN+255)/256, 256, 0, stream>>>(dinv);
    k_scatter<<<(NE+255)/256, 256, 0, stream>>>(esrc, edst, cursor, ebuf);

    // GRU encoder
    k_gru<<<(NN+63)/64, 256, 0, stream>>>(x, W_ip, b_ip, gWi, gWh, gbi, gbh,
                                          Wdyn, bdyn, hist);

    // GCN layer 1
    k_xw<64><<<(NN+255)/256, 256, 0, stream>>>(hist, nullptr, WT1, dinv, xws);
    k_gather<<<(NN+3)/4, 256, 0, stream>>>(rowptr, ebuf, dinv, xws, b_g1, g1);
    // GCN layer 2 (input concat(hist, g1))
    k_xw<128><<<(NN+255)/256, 256, 0, stream>>>(hist, g1, WT2, dinv, xws);
    k_gather<<<(NN+3)/4, 256, 0, stream>>>(rowptr, ebuf, dinv, xws, b_g2, g2);

    // target gather + W_nbr + iga0
    k_target<<<NB, 128, 0, stream>>>(tgt, hist, g1, g2, Wnbr, bnbr, Wi0, bi0, iga0);

    // LSTM decoder (4 rows/block)
    k_lstm<<<NB/4, 512, 0, stream>>>(iga0, bh0, Wh0, Wi1, Wh1, bi1, bh1, hdec);

    // output projection
    k_out<<<(NB*25*2+255)/256, 256, 0, stream>>>(hdec, Wop, bop, out);
}